// Round 23
// baseline (215.172 us; speedup 1.0000x reference)
//
#include <hip/hip_runtime.h>
#include <hip/hip_bf16.h>

// VecLocal2d: x[320][32][32][32] f32, weight[32][32][64][288] f32, bias[10][64][1024] f32
// out[320][64][1024] f32.  Per (h,w): out[m,o] = sum_k patch[m,k]*W[o,k] + bias.
//
// R3: k'=(dy*3+dx)*32+c permutation, xT2[yx][m][c] bf16 staging. R4: load-batch NEUTRAL.
// R5: scatter-store fusion FAILED (write amp 2.5x). R6: operand swap NEUTRAL, kept.
// R7 (measured): A-load dedup -> main 57-58us, total 221. Kept; introduced 4.13M LDS
//   bank conflicts (W reads stride 592B over 16 lanes = 5.6 extra cyc/ds_read_b128).
// R8 (measured): bf16 out_s: WRITE 82->41MB as predicted, absmax unchanged, total 213.4.
//   main dur unchanged -> write stream not on main's critical path; gain was outT reads.
// R9 (third submit; two infra timeouts, never measured): three width/layout fixes:
//   1. main W-LDS layout [tap][c-chunk][o][8c]: per-(kt,quad,tni) 16 lanes read 256B
//      CONTIGUOUS (2-way bank = free) vs 592B-strided. Predict conflicts 4.13M -> <1M.
//   2. outT: out_s loads 8B->16B (ushort8).
//   3. xpose: xT2 stores 8B->16B (ushort8, 8-row gather).
//   Predict main 60->56-58, xpose -4-6us, outT -5-8us, total 213 -> ~197-205.

typedef __attribute__((ext_vector_type(8))) short short8;
typedef __attribute__((ext_vector_type(4))) float f32x4;
typedef __attribute__((ext_vector_type(4))) unsigned short ushort4b;
typedef __attribute__((ext_vector_type(8))) unsigned short ushort8;

#define XT2_ELEMS 10485760             // 1024 yx * 320 m * 32 c
#define ZSLAB_ELEMS 10240              // 320 m * 32 c zero slab for OOB taps
#define OUTS_OFF_BYTES 20992000        // (XT2_ELEMS + ZSLAB_ELEMS)*2 = 20,992,000 B

__device__ __forceinline__ unsigned short f2bf(float f) {
    __hip_bfloat16 b = __float2bfloat16(f);
    return __builtin_bit_cast(unsigned short, b);
}

__device__ __forceinline__ float bf2f(unsigned short u) {
    const unsigned int x = ((unsigned int)u) << 16;
    return __builtin_bit_cast(float, x);
}

// ---- kernel 1: x[mc][yx] f32 -> xT2[yx][mc] bf16  (10240 x 1024 transpose)
__global__ __launch_bounds__(256) void VecLocal2d_xpose(const float* __restrict__ x,
                                                        unsigned short* __restrict__ xT2) {
    __shared__ unsigned short tile[64][68];  // row = 136 B
    if (blockIdx.x == 0) {  // zero slab for out-of-bounds patch taps
#pragma unroll
        for (int j = 0; j < 20; ++j)
            reinterpret_cast<unsigned int*>(xT2 + XT2_ELEMS)[threadIdx.x + j * 256] = 0u;
    }
    const int mcb = blockIdx.x >> 4;   // 160 tiles over mc
    const int yxb = blockIdx.x & 15;   // 16 tiles over yx
    const int t = threadIdx.x;
    const int g = t >> 4;              // 0..15
    const int l4 = (t & 15) * 4;
#pragma unroll
    for (int p = 0; p < 4; ++p) {
        const int ml = g + p * 16;     // mc-local row
        const float4 v = *reinterpret_cast<const float4*>(
            x + (size_t)(mcb * 64 + ml) * 1024 + yxb * 64 + l4);
        ushort4b u;
        u.x = f2bf(v.x); u.y = f2bf(v.y); u.z = f2bf(v.z); u.w = f2bf(v.w);
        *reinterpret_cast<ushort4b*>(&tile[ml][l4]) = u;
    }
    __syncthreads();
    // R9: 16B stores — each thread gathers 8 tile rows for one yx row.
#pragma unroll
    for (int p = 0; p < 2; ++p) {
        const int idx = p * 256 + t;      // 0..511
        const int yl = idx >> 3;          // 0..63 yx-local row
        const int l8 = (idx & 7) * 8;     // 0..56 mc chunk
        ushort8 u;
#pragma unroll
        for (int e = 0; e < 8; ++e) u[e] = tile[l8 + e][yl];
        *reinterpret_cast<ushort8*>(xT2 + (size_t)(yxb * 64 + yl) * 10240 + mcb * 64 + l8) = u;
    }
}

// ---- kernel 2: main GEMM per location; A-frags straight from global, no inner barriers
__global__ __launch_bounds__(256, 4) void VecLocal2d_main(const unsigned short* __restrict__ xT2,
                                                          const float* __restrict__ weight,
                                                          unsigned short* __restrict__ out_s) {
    // R9 layout: wLDS[(tap r)*4 + (c>>3)][o][c&7] -> lane-contiguous 256B reads.
    __shared__ unsigned short wLDS[18432];   // 9 taps * 4 c-chunks * 64 o * 8 = 36.9 KB

    // XCD swizzle: neighbors in (h,w) share XCD for xT2 L2 reuse.
    const int bid = blockIdx.x;
    const int s = bid >> 7;
    const int hg = bid & 127;
    const int h = hg >> 2;
    const int w = ((hg & 3) << 3) | s;
    const int loc = h * 32 + w;

    const int tid = threadIdx.x;
    const int lane = tid & 63;
    const int wave = tid >> 6;         // wave = m16 slice (0..3)
    const int quad = lane >> 4;        // k-chunk selector
    const int l16 = lane & 15;         // row selector (m for A, o for W)

    // ---- stage weight (64*288 f32, contiguous reads) -> wLDS bf16, R9-permuted ----
    const float* wg = weight + (size_t)loc * 18432;
#pragma unroll
    for (int i = 0; i < 18; ++i) {
        const int f4i = tid + i * 256;
        const float4 v = reinterpret_cast<const float4*>(wg)[f4i];
        const int o = f4i / 72;
        const int kbase = (f4i - o * 72) * 4;
        const float vv[4] = {v.x, v.y, v.z, v.w};
#pragma unroll
        for (int e = 0; e < 4; ++e) {
            const int k = kbase + e;       // original k = c*9 + r
            const int c = k / 9;
            const int r = k - c * 9;
            wLDS[(r * 4 + (c >> 3)) * 512 + o * 8 + (c & 7)] = f2bf(vv[e]);
        }
    }

    // ---- 9 neighbor base offsets (block-uniform -> SGPRs); OOB -> zero slab ----
    int base[9];
#pragma unroll
    for (int dy = 0; dy < 3; ++dy)
#pragma unroll
        for (int dx = 0; dx < 3; ++dx) {
            const int y = h - 1 + dy;
            const int xc = w - 1 + dx;
            const bool valid = ((unsigned)y < 32u) && ((unsigned)xc < 32u);
            base[dy * 3 + dx] = valid ? (y * 32 + xc) * 10240 : XT2_ELEMS;
        }

    __syncthreads();

    // R9: per-lane W base; per-(kt,tni) the 16 lanes read 256B contiguous.
    const unsigned short* wl = &wLDS[quad * 512 + l16 * 8];
    const int laneA = (wave * 16 + l16) * 32 + quad * 8;  // + mt*2048
    unsigned short* os = out_s + (size_t)loc * 20480;

    for (int mt = 0; mt < 5; ++mt) {
        const int moff = laneA + mt * 2048;
        f32x4 acc[4] = {};
#pragma unroll
        for (int kt = 0; kt < 9; ++kt) {
            const short8 a = *reinterpret_cast<const short8*>(xT2 + base[kt] + moff);
#pragma unroll
            for (int tni = 0; tni < 4; ++tni) {
                const short8 b = *reinterpret_cast<const short8*>(wl + kt * 2048 + tni * 128);
                acc[tni] = __builtin_amdgcn_mfma_f32_16x16x32_bf16(b, a, acc[tni], 0, 0, 0);
            }
        }

        // Swapped-D: col(=m_local)=l16, row(=o_local)=quad*4+r.
        // bf16 out_s: one ushort4 (8B) store per tni; wave covers contiguous 128B per m-row.
        const int m = mt * 64 + wave * 16 + l16;
#pragma unroll
        for (int tni = 0; tni < 4; ++tni) {
            ushort4b u;
            u.x = f2bf(acc[tni][0]);
            u.y = f2bf(acc[tni][1]);
            u.z = f2bf(acc[tni][2]);
            u.w = f2bf(acc[tni][3]);
            *reinterpret_cast<ushort4b*>(&os[m * 64 + tni * 16 + quad * 4]) = u;
        }
    }
}

// ---- kernel 3: out_s bf16 [loc][m*64+o] -> out f32 [(m*64+o)*1024+loc], bias fused.
__global__ __launch_bounds__(256) void VecLocal2d_outT(const unsigned short* __restrict__ out_s,
                                                       const float* __restrict__ bias,
                                                       float* __restrict__ out) {
    __shared__ float tile[64][65];
    const int m = blockIdx.x >> 4;
    const int loc0 = (blockIdx.x & 15) * 64;
    const int t = threadIdx.x;
    const unsigned short* src = out_s + (size_t)loc0 * 20480 + m * 64;
    // R9: 16B loads — each thread reads 8 consecutive o of one loc row.
#pragma unroll
    for (int p = 0; p < 2; ++p) {
        const int idx = p * 256 + t;      // 0..511
        const int lr = idx >> 3;          // loc within tile
        const int c8 = (idx & 7) * 8;     // o chunk
        const ushort8 v = *reinterpret_cast<const ushort8*>(src + (size_t)lr * 20480 + c8);
#pragma unroll
        for (int e = 0; e < 8; ++e) tile[lr][c8 + e] = bf2f(v[e]);
    }
    __syncthreads();
    const int cat = m % 10;
#pragma unroll
    for (int p = 0; p < 4; ++p) {
        const int idx = p * 256 + t;
        const int o = idx >> 4;           // o within tile
        const int l4 = (idx & 15) * 4;    // loc chunk
        const float4 bv = *reinterpret_cast<const float4*>(
            bias + ((size_t)(cat * 64 + o)) * 1024 + loc0 + l4);
        float4 v;
        v.x = tile[l4 + 0][o] + bv.x;
        v.y = tile[l4 + 1][o] + bv.y;
        v.z = tile[l4 + 2][o] + bv.z;
        v.w = tile[l4 + 3][o] + bv.w;
        *reinterpret_cast<float4*>(out + ((size_t)(m * 64 + o)) * 1024 + loc0 + l4) = v;
    }
}

extern "C" void kernel_launch(void* const* d_in, const int* in_sizes, int n_in,
                              void* d_out, int out_size, void* d_ws, size_t ws_size,
                              hipStream_t stream) {
    const float* x = (const float*)d_in[0];
    const float* wgt = (const float*)d_in[1];
    const float* bias = (const float*)d_in[2];
    float* out = (float*)d_out;
    unsigned short* xT2 = (unsigned short*)d_ws;                           // 21.0 MB (+20KB slab)
    unsigned short* out_s = (unsigned short*)((char*)d_ws + OUTS_OFF_BYTES); // 41.9 MB bf16

    VecLocal2d_xpose<<<2560, 256, 0, stream>>>(x, xT2);
    VecLocal2d_main<<<1024, 256, 0, stream>>>(xT2, wgt, out_s);
    VecLocal2d_outT<<<5120, 256, 0, stream>>>(out_s, bias, out);
}